// Round 6
// baseline (400.585 us; speedup 1.0000x reference)
//
#include <hip/hip_runtime.h>
#include <math.h>

#define N_NODES 50000
#define D       64
#define N_EDGES 800000
#define N_HEAD  4

typedef unsigned short ushort_t;

// bf16 <-> fp32 bit helpers (RNE on pack)
__device__ __forceinline__ float bf_lo(unsigned u) {
    return __uint_as_float(u << 16);
}
__device__ __forceinline__ float bf_hi(unsigned u) {
    return __uint_as_float(u & 0xffff0000u);
}
__device__ __forceinline__ ushort_t f2bf(float f) {
    unsigned u = __float_as_uint(f);
    u += 0x7fffu + ((u >> 16) & 1u);   // round-to-nearest-even
    return (ushort_t)(u >> 16);
}

// ---------------------------------------------------------------------------
// prep: row_ptr (binary search over sorted edge_row) + (col,val) pack
// ---------------------------------------------------------------------------
__global__ void prep_kernel(const int* __restrict__ edge_row,
                            const int* __restrict__ edge_col,
                            const float* __restrict__ edge_val,
                            int* __restrict__ row_ptr,
                            int2* __restrict__ cv) {
    const int i = blockIdx.x * blockDim.x + threadIdx.x;
    if (i < N_EDGES) cv[i] = make_int2(edge_col[i], __float_as_int(edge_val[i]));
    if (i <= N_NODES) {
        int lo = 0, hi = N_EDGES;
        while (lo < hi) {
            int mid = (lo + hi) >> 1;
            if (edge_row[mid] < i) lo = mid + 1; else hi = mid;
        }
        row_ptr[i] = lo;
    }
}

// ---------------------------------------------------------------------------
// head-0 linear: t[n][j] = bf16( elu( sum_k (mask? x[n][k]:0) * W[j][k] + b[j] ) )
// lane j holds W[j][*] in 64 VGPRs; row data via wave-uniform scalar loads.
// ---------------------------------------------------------------------------
__global__ __launch_bounds__(256) void linear_elu_kernel(
        const float* __restrict__ in,
        const float* __restrict__ W,
        const float* __restrict__ b,
        const int*  __restrict__ et,
        ushort_t* __restrict__ t) {
    const int lane = threadIdx.x & 63;
    const int wid  = (blockIdx.x * blockDim.x + threadIdx.x) >> 6;
    const int nwav = (gridDim.x * blockDim.x) >> 6;

    float4 w4[16];
    {
        const float4* wp = (const float4*)(W + lane * D);
        #pragma unroll
        for (int i = 0; i < 16; ++i) w4[i] = wp[i];
    }
    const float* w = (const float*)w4;
    const float bj = b[lane];

    for (int row0 = wid; row0 < N_NODES; row0 += nwav) {
        const int row = __builtin_amdgcn_readfirstlane(row0);
        float acc = bj;
        if (et[row] != 0) {
            const float* rp = in + (size_t)row * D;
            #pragma unroll
            for (int k = 0; k < D; ++k)
                acc = fmaf(rp[k], w[k], acc);
        }
        const float e = (acc > 0.f) ? acc : expm1f(acc);
        t[(size_t)row * D + lane] = f2bf(e);
    }
}

// ---------------------------------------------------------------------------
// Fused: h = spmm(tin); out (+)= h; if DO_LINEAR: tout = bf16(elu(h@W^T + b)).
// One wave per row; 4 groups of 16 lanes; group g, slot u handles edge
// e+4u+g. Gathers are exec-masked (v==0 slots issue NO memory traffic) and
// batched before all consumers (8 gathers in flight). After the XOR-reduce
// every lane holds the row sum for dims [4l,4l+4); g==0 lanes write out and
// stage the row in per-wave LDS; all 64 lanes then run the next head's
// linear (W[j][*] in 64 VGPRs) + ELU and store bf16 tout.
// h never touches global memory; kernel boundary = the t_i -> t_{i+1} barrier.
// ---------------------------------------------------------------------------
template<int DO_LINEAR>
__global__ __launch_bounds__(256, 4) void fused_kernel(
        const ushort_t* __restrict__ tin,   // bf16 [N][64]
        ushort_t* __restrict__ tout,        // bf16 [N][64] (other buffer)
        const float* __restrict__ W,        // next head's W (if DO_LINEAR)
        const float* __restrict__ bvec,
        const int2* __restrict__ cv,
        const int*  __restrict__ row_ptr,
        float* __restrict__ out,
        int first_head) {
    __shared__ float rowbuf[4][64];
    const int tid   = threadIdx.x;
    const int lane  = tid & 63;
    const int wslot = tid >> 6;
    const int g     = lane >> 4;
    const int l     = lane & 15;

    float4 w4[16];
    float bj = 0.f;
    if (DO_LINEAR) {
        const float4* wp = (const float4*)(W + lane * D);
        #pragma unroll
        for (int i = 0; i < 16; ++i) w4[i] = wp[i];
        bj = bvec[lane];
    }
    const float* w = (const float*)w4;

    const int row0 = (blockIdx.x * blockDim.x + tid) >> 6;
    if (row0 >= N_NODES) return;
    const int row = __builtin_amdgcn_readfirstlane(row0);

    const int e0 = row_ptr[row];
    const int e1 = row_ptr[row + 1];
    float4 acc = {0.f, 0.f, 0.f, 0.f};

    for (int e = e0; e < e1; e += 32) {
        int   c[8];
        float v[8];
        #pragma unroll
        for (int u = 0; u < 8; ++u) {
            const int  ce = e + 4 * u + g;
            const int  cc = (ce < e1) ? ce : (e1 - 1);
            const int2 p  = cv[cc];
            c[u] = p.x;
            v[u] = (ce < e1) ? __int_as_float(p.y) : 0.f;
        }
        uint2 r2[8];
        #pragma unroll
        for (int u = 0; u < 8; ++u) r2[u] = make_uint2(0u, 0u);
        // loads only, no consumers -> all active gathers issue back-to-back
        #pragma unroll
        for (int u = 0; u < 8; ++u)
            if (v[u] != 0.f)
                r2[u] = *(const uint2*)(tin + (size_t)c[u] * D + l * 4);
        #pragma unroll
        for (int u = 0; u < 8; ++u) {
            acc.x = fmaf(v[u], bf_lo(r2[u].x), acc.x);
            acc.y = fmaf(v[u], bf_hi(r2[u].x), acc.y);
            acc.z = fmaf(v[u], bf_lo(r2[u].y), acc.z);
            acc.w = fmaf(v[u], bf_hi(r2[u].y), acc.w);
        }
    }

    // butterfly: afterwards EVERY lane holds the row total for its dim quad
    #pragma unroll
    for (int off = 16; off < 64; off <<= 1) {
        acc.x += __shfl_xor(acc.x, off, 64);
        acc.y += __shfl_xor(acc.y, off, 64);
        acc.z += __shfl_xor(acc.z, off, 64);
        acc.w += __shfl_xor(acc.w, off, 64);
    }

    if (g == 0) {
        const size_t base = (size_t)row * D + (size_t)l * 4;
        if (first_head) {
            *(float4*)(out + base) = acc;
        } else {
            float4 o = *(const float4*)(out + base);
            o.x += acc.x; o.y += acc.y; o.z += acc.z; o.w += acc.w;
            *(float4*)(out + base) = o;
        }
        if (DO_LINEAR) *(float4*)&rowbuf[wslot][l * 4] = acc;
    }

    if (DO_LINEAR) {
        // same wave wrote rowbuf; program order + lgkmcnt makes it visible
        float lacc = bj;
        #pragma unroll
        for (int k = 0; k < 16; ++k) {
            const float4 r = *(const float4*)&rowbuf[wslot][k * 4];
            lacc = fmaf(r.x, w[4 * k + 0], lacc);
            lacc = fmaf(r.y, w[4 * k + 1], lacc);
            lacc = fmaf(r.z, w[4 * k + 2], lacc);
            lacc = fmaf(r.w, w[4 * k + 3], lacc);
        }
        const float eo = (lacc > 0.f) ? lacc : expm1f(lacc);
        tout[(size_t)row * D + lane] = f2bf(eo);
    }
}

// ---------------------------------------------------------------------------
extern "C" void kernel_launch(void* const* d_in, const int* in_sizes, int n_in,
                              void* d_out, int out_size, void* d_ws, size_t ws_size,
                              hipStream_t stream) {
    const float* x        = (const float*)d_in[0];  // [N, 64]
    const float* edge_val = (const float*)d_in[1];  // [E]
    const float* W        = (const float*)d_in[2];  // [4, 64, 64]
    const float* b        = (const float*)d_in[3];  // [4, 64]
    const int* edge_row   = (const int*)d_in[4];    // sorted
    const int* edge_col   = (const int*)d_in[5];
    const int* event_type = (const int*)d_in[6];    // [N] (int32 on device)
    float* out = (float*)d_out;

    // ws layout: cv[E] (8B) | row_ptr[N+2] | tA bf16 | tB bf16
    char* p = (char*)d_ws;
    int2*     cv      = (int2*)p;                     p += (size_t)N_EDGES * 8;
    int*      row_ptr = (int*)p;                      p += (size_t)(N_NODES + 2) * 4;
    p = (char*)(((uintptr_t)p + 15) & ~(uintptr_t)15);
    ushort_t* tA      = (ushort_t*)p;                 p += (size_t)N_NODES * D * 2;
    ushort_t* tB      = (ushort_t*)p;

    prep_kernel<<<(N_EDGES + 255) / 256, 256, 0, stream>>>(
        edge_row, edge_col, edge_val, row_ptr, cv);

    // head 0 linear+elu: x(masked) -> tA
    linear_elu_kernel<<<1024, 256, 0, stream>>>(
        x, W, b, event_type, tA);

    const int nblk = N_NODES / 4;  // one wave per row, 4 waves/block
    // head0 spmm + head1 linear
    fused_kernel<1><<<nblk, 256, 0, stream>>>(
        tA, tB, W + 1 * D * D, b + 1 * D, cv, row_ptr, out, 1);
    // head1 spmm + head2 linear
    fused_kernel<1><<<nblk, 256, 0, stream>>>(
        tB, tA, W + 2 * D * D, b + 2 * D, cv, row_ptr, out, 0);
    // head2 spmm + head3 linear
    fused_kernel<1><<<nblk, 256, 0, stream>>>(
        tA, tB, W + 3 * D * D, b + 3 * D, cv, row_ptr, out, 0);
    // head3 spmm only
    fused_kernel<0><<<nblk, 256, 0, stream>>>(
        tB, nullptr, nullptr, nullptr, cv, row_ptr, out, 0);
}

// Round 7
// 193.057 us; speedup vs baseline: 2.0750x; 2.0750x over previous
//
#include <hip/hip_runtime.h>
#include <math.h>

#define N_NODES 50000
#define D       64
#define N_EDGES 800000
#define N_HEAD  4

typedef unsigned short ushort_t;
typedef unsigned int   uint_t;

// bf16 <-> fp32 bit helpers (RNE on pack)
__device__ __forceinline__ float bf_lo(uint_t u) {
    return __uint_as_float(u << 16);
}
__device__ __forceinline__ float bf_hi(uint_t u) {
    return __uint_as_float(u & 0xffff0000u);
}
__device__ __forceinline__ ushort_t f2bf(float f) {
    uint_t u = __float_as_uint(f);
    u += 0x7fffu + ((u >> 16) & 1u);   // round-to-nearest-even
    return (ushort_t)(u >> 16);
}

// ---------------------------------------------------------------------------
// prep: cv[e] = (col<<16) | bf16(val)  (col < 50000 fits 16 bits);
//       row_ptr[r] = lower_bound(edge_row, r) (edge_row sorted)
// ---------------------------------------------------------------------------
__global__ void prep_kernel(const int* __restrict__ edge_row,
                            const int* __restrict__ edge_col,
                            const float* __restrict__ edge_val,
                            int* __restrict__ row_ptr,
                            uint_t* __restrict__ cv) {
    const int i = blockIdx.x * blockDim.x + threadIdx.x;
    if (i < N_EDGES)
        cv[i] = ((uint_t)edge_col[i] << 16) | (uint_t)f2bf(edge_val[i]);
    if (i <= N_NODES) {
        int lo = 0, hi = N_EDGES;
        while (lo < hi) {
            int mid = (lo + hi) >> 1;
            if (edge_row[mid] < i) lo = mid + 1; else hi = mid;
        }
        row_ptr[i] = lo;
    }
}

// ---------------------------------------------------------------------------
// t[n][j] = bf16( elu( sum_k in[n][k] * W[j][k] + b[j] ) )
// lane j holds W[j][*] in 64 VGPRs; row data via wave-uniform scalar loads.
// BF16IN=0: fp32 input with event_type mask (head 0). BF16IN=1: bf16 h input.
// ---------------------------------------------------------------------------
template<int BF16IN>
__global__ __launch_bounds__(256) void linear_elu_kernel(
        const void* __restrict__ in,
        const float* __restrict__ W,   // [64][64] row-major, W[j][k]
        const float* __restrict__ b,   // [64]
        const int*  __restrict__ et,   // mask if et[n]==0 (BF16IN=0 only)
        ushort_t* __restrict__ t) {
    const int lane = threadIdx.x & 63;
    const int wid  = (blockIdx.x * blockDim.x + threadIdx.x) >> 6;
    const int nwav = (gridDim.x * blockDim.x) >> 6;

    float4 w4[16];
    {
        const float4* wp = (const float4*)(W + lane * D);
        #pragma unroll
        for (int i = 0; i < 16; ++i) w4[i] = wp[i];
    }
    const float* w = (const float*)w4;
    const float bj = b[lane];

    for (int row0 = wid; row0 < N_NODES; row0 += nwav) {
        const int row = __builtin_amdgcn_readfirstlane(row0);
        float acc = bj;
        if (BF16IN) {
            const uint_t* rp = (const uint_t*)in + (size_t)row * 32;
            #pragma unroll
            for (int k2 = 0; k2 < 32; ++k2) {
                const uint_t u = rp[k2];
                acc = fmaf(bf_lo(u), w[2 * k2 + 0], acc);
                acc = fmaf(bf_hi(u), w[2 * k2 + 1], acc);
            }
        } else {
            if (et[row] != 0) {
                const float* rp = (const float*)in + (size_t)row * D;
                #pragma unroll
                for (int k = 0; k < D; ++k)
                    acc = fmaf(rp[k], w[k], acc);
            }
        }
        const float e = (acc > 0.f) ? acc : expm1f(acc);
        t[(size_t)row * D + lane] = f2bf(e);
    }
}

// ---------------------------------------------------------------------------
// SpMM: h[r][:] = sum_{e in row r} val[e] * t[col[e]][:]   (t bf16, cv packed)
// One wave per row; 4 groups of 16 lanes; group g, slot u -> edge e+4u+g.
// Two masked 16-edge chunks: chunk A always, chunk B under a WAVE-UNIFORM
// branch (deg<=16 rows skip it entirely -> no dummy traffic). All metadata
// loads issue before all gathers -> 2 dependent memory rounds per row for
// 99.99% of rows. Dummy slots clamp to edge e1-1 (its t-row is L2-hot).
// Deg>32 tail loop is ~1e-4 of rows.
// ---------------------------------------------------------------------------
__global__ __launch_bounds__(256) void spmm_kernel(
        const ushort_t* __restrict__ tin,   // bf16 [N][64]
        const uint_t* __restrict__ cv,      // (col<<16)|bf16(val) [E]
        const int*   __restrict__ row_ptr,
        ushort_t* __restrict__ h,           // bf16 [N][64] (if write_h)
        float* __restrict__ out,
        int first_head, int write_h) {
    const int lane = threadIdx.x & 63;
    const int g    = lane >> 4;    // edge slot within quad
    const int l    = lane & 15;    // dim quad: dims [4l, 4l+4)
    const int row0 = (blockIdx.x * blockDim.x + threadIdx.x) >> 6;
    if (row0 >= N_NODES) return;
    const int row = __builtin_amdgcn_readfirstlane(row0);

    const int e0 = row_ptr[row];
    const int e1 = row_ptr[row + 1];
    const int eclamp = (e1 > 0) ? e1 - 1 : 0;   // valid dummy index
    float4 acc = {0.f, 0.f, 0.f, 0.f};

    int   cA[4], cB[4];
    float vA[4], vB[4];
    uint2 rA[4], rB[4];
    const bool haveB = (e0 + 16) < e1;   // wave-uniform

    // metadata round: A (and B) concurrently in flight
    #pragma unroll
    for (int u = 0; u < 4; ++u) {
        const int  ce = e0 + 4 * u + g;
        const bool ok = ce < e1;
        const uint_t p = cv[ok ? ce : eclamp];
        cA[u] = (int)(p >> 16);
        vA[u] = ok ? bf_lo(p) : 0.f;
    }
    if (haveB) {
        #pragma unroll
        for (int u = 0; u < 4; ++u) {
            const int  ce = e0 + 16 + 4 * u + g;
            const bool ok = ce < e1;
            const uint_t p = cv[ok ? ce : eclamp];
            cB[u] = (int)(p >> 16);
            vB[u] = ok ? bf_lo(p) : 0.f;
        }
    }
    // gather round: up to 8 gathers in flight
    #pragma unroll
    for (int u = 0; u < 4; ++u)
        rA[u] = *(const uint2*)(tin + (size_t)cA[u] * D + l * 4);
    if (haveB) {
        #pragma unroll
        for (int u = 0; u < 4; ++u)
            rB[u] = *(const uint2*)(tin + (size_t)cB[u] * D + l * 4);
    }
    // consume
    #pragma unroll
    for (int u = 0; u < 4; ++u) {
        acc.x = fmaf(vA[u], bf_lo(rA[u].x), acc.x);
        acc.y = fmaf(vA[u], bf_hi(rA[u].x), acc.y);
        acc.z = fmaf(vA[u], bf_lo(rA[u].y), acc.z);
        acc.w = fmaf(vA[u], bf_hi(rA[u].y), acc.w);
    }
    if (haveB) {
        #pragma unroll
        for (int u = 0; u < 4; ++u) {
            acc.x = fmaf(vB[u], bf_lo(rB[u].x), acc.x);
            acc.y = fmaf(vB[u], bf_hi(rB[u].x), acc.y);
            acc.z = fmaf(vB[u], bf_lo(rB[u].y), acc.z);
            acc.w = fmaf(vB[u], bf_hi(rB[u].y), acc.w);
        }
    }
    // rare tail: deg > 32
    for (int e = e0 + 32; e < e1; e += 16) {
        #pragma unroll
        for (int u = 0; u < 4; ++u) {
            const int  ce = e + 4 * u + g;
            const bool ok = ce < e1;
            const uint_t p = cv[ok ? ce : eclamp];
            const int   c = (int)(p >> 16);
            const float v = ok ? bf_lo(p) : 0.f;
            const uint2 r = *(const uint2*)(tin + (size_t)c * D + l * 4);
            acc.x = fmaf(v, bf_lo(r.x), acc.x);
            acc.y = fmaf(v, bf_hi(r.x), acc.y);
            acc.z = fmaf(v, bf_lo(r.y), acc.z);
            acc.w = fmaf(v, bf_hi(r.y), acc.w);
        }
    }

    // reduce across the 4 groups (lanes differing in bits 4,5)
    #pragma unroll
    for (int off = 16; off < 64; off <<= 1) {
        acc.x += __shfl_xor(acc.x, off, 64);
        acc.y += __shfl_xor(acc.y, off, 64);
        acc.z += __shfl_xor(acc.z, off, 64);
        acc.w += __shfl_xor(acc.w, off, 64);
    }

    if (g == 0) {
        const size_t base = (size_t)row * D + (size_t)l * 4;
        if (first_head) {
            *(float4*)(out + base) = acc;
        } else {
            float4 o = *(const float4*)(out + base);
            o.x += acc.x; o.y += acc.y; o.z += acc.z; o.w += acc.w;
            *(float4*)(out + base) = o;
        }
        if (write_h) {
            uint2 hp;
            hp.x = (uint_t)f2bf(acc.x) | ((uint_t)f2bf(acc.y) << 16);
            hp.y = (uint_t)f2bf(acc.z) | ((uint_t)f2bf(acc.w) << 16);
            *(uint2*)(h + base) = hp;
        }
    }
}

// ---------------------------------------------------------------------------
extern "C" void kernel_launch(void* const* d_in, const int* in_sizes, int n_in,
                              void* d_out, int out_size, void* d_ws, size_t ws_size,
                              hipStream_t stream) {
    const float* x        = (const float*)d_in[0];  // [N, 64]
    const float* edge_val = (const float*)d_in[1];  // [E]
    const float* W        = (const float*)d_in[2];  // [4, 64, 64]
    const float* b        = (const float*)d_in[3];  // [4, 64]
    const int* edge_row   = (const int*)d_in[4];    // sorted
    const int* edge_col   = (const int*)d_in[5];
    const int* event_type = (const int*)d_in[6];    // [N] (int32 on device)
    float* out = (float*)d_out;

    // ws: cv uint32[E] | row_ptr[N+2] | t bf16[N*64] | h bf16[N*64]
    char* p = (char*)d_ws;
    uint_t*   cv      = (uint_t*)p;                  p += (size_t)N_EDGES * 4;
    int*      row_ptr = (int*)p;                     p += (size_t)(N_NODES + 2) * 4;
    p = (char*)(((uintptr_t)p + 15) & ~(uintptr_t)15);
    ushort_t* t       = (ushort_t*)p;                p += (size_t)N_NODES * D * 2;
    ushort_t* h       = (ushort_t*)p;

    prep_kernel<<<(N_EDGES + 255) / 256, 256, 0, stream>>>(
        edge_row, edge_col, edge_val, row_ptr, cv);

    const int sblk = (N_NODES * 64 + 255) / 256;

    // head 0: linear(x fp32, masked) -> t ; spmm(t) -> h, out =
    linear_elu_kernel<0><<<1024, 256, 0, stream>>>(x, W, b, event_type, t);
    spmm_kernel<<<sblk, 256, 0, stream>>>(t, cv, row_ptr, h, out, 1, 1);

    // heads 1..3: linear(h bf16) -> t ; spmm(t) -> h, out +=
    for (int i = 1; i < N_HEAD; ++i) {
        linear_elu_kernel<1><<<1024, 256, 0, stream>>>(
            h, W + (size_t)i * D * D, b + (size_t)i * D, nullptr, t);
        spmm_kernel<<<sblk, 256, 0, stream>>>(
            t, cv, row_ptr, h, out, 0, (i < N_HEAD - 1) ? 1 : 0);
    }
}